// Round 15
// baseline (89.280 us; speedup 1.0000x reference)
//
#include <hip/hip_runtime.h>
#include <math.h>

#define B_    2
#define S_    512
#define HDIM  1024
#define D_    24      // proj dim
#define M_    96      // pair-MLP hidden
#define ROWS  (B_*S_) // 1024

typedef _Float16 half8 __attribute__((ext_vector_type(8)));
typedef float    f32x4 __attribute__((ext_vector_type(4)));
typedef unsigned short ushort8 __attribute__((ext_vector_type(8)));

// ---------------------------------------------------------------------------
// cache-based 64x64 fp32->fp16 transpose, 256 threads (no LDS)
// ---------------------------------------------------------------------------
__device__ __forceinline__ void transpose_tile64_cache(
    const float* __restrict__ in, _Float16* __restrict__ out,
    int R, int C, int xt, int yt, int t) {
  int R0 = yt * 64, C0 = xt * 64;
  int c = t >> 2, rq = (t & 3) * 16;
  _Float16 o[16];
  const float* src = in + (size_t)(R0 + rq) * C + C0 + c;
#pragma unroll
  for (int e = 0; e < 16; ++e) o[e] = (_Float16)src[(size_t)e * C];
  _Float16* dst = out + (size_t)(C0 + c) * R + R0 + rq;
  *(ushort8*)dst = *(ushort8*)o;
  *(ushort8*)(dst + 8) = *(ushort8*)&o[8];
}

// ---------------------------------------------------------------------------
// MFMA projection, 64 rows per block (4 waves x 16 rows). P ([1024][24] fp32)
// staged inline into LDS fp16 B-fragments in two 16-step phases (32KB).
// Emits fp16 image of H rows. If DOBI: also emits Bi = Z @ W1[24:48]
// (fp32 [rows][96]) via a 2-barrier MFMA epilogue (Zi already in acc regs).
// ---------------------------------------------------------------------------
template <bool DOBI>
__device__ __forceinline__ void proj_mfma64(
    const float* __restrict__ H, const float* __restrict__ P,
    const float* __restrict__ W1,
    float* __restrict__ Z, _Float16* __restrict__ Himg,
    float* __restrict__ Bi, int r0, char* smem, int t) {
  const int w = t >> 6, l = t & 63;
  const int lo = l & 15, hi = l >> 4;
  const int row = r0 + w * 16 + lo;
  const float* hrow = H + (size_t)row * HDIM;
  f32x4 acc0 = {}, acc1 = {};

  for (int ph = 0; ph < 2; ++ph) {
    if (ph) __syncthreads();   // all waves done reading phase-0 fragments
    for (int q = 0; q < 8; ++q) {
      int s = t + q * 256;
      int slo = s & 15, shi = (s >> 4) & 3, snt = (s >> 6) & 1, sst = s >> 7;
      int d = snt * 16 + slo;
      half8 v = {};
      if (d < D_) {
        int k = (ph * 16 + sst) * 32 + shi * 8;
#pragma unroll
        for (int e = 0; e < 8; ++e)
          v[e] = (_Float16)P[(size_t)(k + e) * D_ + d];
      }
      *(half8*)(smem + s * 16) = v;
    }
    __syncthreads();

    for (int st = 0; st < 16; ++st) {
      int step = ph * 16 + st;
      const float* src = hrow + step * 32 + hi * 8;
      float4 v0 = *(const float4*)src;
      float4 v1 = *(const float4*)(src + 4);
      half8 a8;
      a8[0] = (_Float16)v0.x; a8[1] = (_Float16)v0.y;
      a8[2] = (_Float16)v0.z; a8[3] = (_Float16)v0.w;
      a8[4] = (_Float16)v1.x; a8[5] = (_Float16)v1.y;
      a8[6] = (_Float16)v1.z; a8[7] = (_Float16)v1.w;
      *(half8*)(Himg + (size_t)row * HDIM + step * 32 + hi * 8) = a8;
      half8 b0 = *(const half8*)(smem + ((st * 2 + 0) * 64 + l) * 16);
      half8 b1 = *(const half8*)(smem + ((st * 2 + 1) * 64 + l) * 16);
      acc0 = __builtin_amdgcn_mfma_f32_16x16x32_f16(a8, b0, acc0, 0, 0, 0);
      acc1 = __builtin_amdgcn_mfma_f32_16x16x32_f16(a8, b1, acc1, 0, 0, 0);
    }
  }
#pragma unroll
  for (int rg = 0; rg < 4; ++rg) {
    int zr = r0 + w * 16 + hi * 4 + rg;
    Z[(size_t)zr * D_ + lo] = acc0[rg];
    if (lo < 8) Z[(size_t)zr * D_ + 16 + lo] = acc1[rg];
  }

  if (DOBI) {
    // Bi[i][m] = sum_d Zi[i][d] * W1[24+d][m]  (K=24 pad 32, N=96, M=64 rows)
    __syncthreads();   // P fragments dead; reuse smem for Zi A-fragments
    _Float16* ldsZ = (_Float16*)smem;   // [64][32]
#pragma unroll
    for (int rg = 0; rg < 4; ++rg) {
      int rr = w * 16 + hi * 4 + rg;
      ldsZ[rr * 32 + lo] = (_Float16)acc0[rg];
      ldsZ[rr * 32 + 16 + lo] = (lo < 8) ? (_Float16)acc1[rg] : (_Float16)0.0f;
    }
    __syncthreads();
    half8 a8 = *(const half8*)(&ldsZ[(w * 16 + lo) * 32 + hi * 8]);
#pragma unroll
    for (int n6 = 0; n6 < 6; ++n6) {
      half8 b8;
#pragma unroll
      for (int e = 0; e < 8; ++e) {
        int d = hi * 8 + e;
        b8[e] = (d < D_) ? (_Float16)W1[(D_ + d) * M_ + n6 * 16 + lo]
                         : (_Float16)0.0f;
      }
      f32x4 accB = {};
      accB = __builtin_amdgcn_mfma_f32_16x16x32_f16(a8, b8, accB, 0, 0, 0);
#pragma unroll
      for (int rg = 0; rg < 4; ++rg)
        Bi[(size_t)(r0 + w * 16 + hi * 4 + rg) * M_ + n6 * 16 + lo] = accB[rg];
    }
  }
}

// ---------------------------------------------------------------------------
// Merged prep kernel (804 blocks):
//  [0,16)    : proj Zj + HjH emit
//  [16,32)   : proj Zi + HiH emit + Bi emit
//  [32,36)   : Wimg (fp16 image of W1 rows 48..95, chunk kc*96+m, kc<6)
//  [36,292)  : Wv1aT tiles   [292,548) : Wv1bT   [548,804) : Wv2T
// ---------------------------------------------------------------------------
__global__ __launch_bounds__(256) void prep_kernel(
    const float* __restrict__ Hj, const float* __restrict__ Hi,
    const float* __restrict__ pj, const float* __restrict__ pi,
    const float* __restrict__ W1, const float* __restrict__ Wv1,
    const float* __restrict__ Wv2,
    _Float16* __restrict__ HjH, _Float16* __restrict__ HiH,
    _Float16* __restrict__ Wv1aT, _Float16* __restrict__ Wv1bT,
    _Float16* __restrict__ Wv2T, _Float16* __restrict__ Wimg,
    float* __restrict__ Zj, float* __restrict__ Zi,
    float* __restrict__ BiF) {
  __shared__ __attribute__((aligned(16))) char smem[32768];
  const int bid = blockIdx.x;
  const int t = threadIdx.x;

  if (bid < 16) {
    proj_mfma64<false>(Hj, pj, W1, Zj, HjH, nullptr, bid * 64, smem, t);
  } else if (bid < 32) {
    proj_mfma64<true>(Hi, pi, W1, Zi, HiH, BiF, (bid - 16) * 64, smem, t);
  } else if (bid < 36) {
    int c = (bid - 32) * 256 + t;   // 0..1023
    half8 v = {};
    if (c < 576) {
      int kc = c / 96, m = c - kc * 96;
#pragma unroll
      for (int e = 0; e < 8; ++e)
        v[e] = (_Float16)W1[(48 + kc * 8 + e) * M_ + m];
    }
    *(half8*)(Wimg + (size_t)c * 8) = v;
  } else if (bid < 292) {
    int id = bid - 36;                 // 16 x 16 tiles
    transpose_tile64_cache(Wv1, Wv1aT, HDIM, HDIM, id & 15, id >> 4, t);
  } else if (bid < 548) {
    int id = bid - 292;
    transpose_tile64_cache(Wv1 + (size_t)HDIM * HDIM, Wv1bT, HDIM, HDIM,
                           id & 15, id >> 4, t);
  } else {
    int id = bid - 548;
    transpose_tile64_cache(Wv2, Wv2T, HDIM, HDIM, id & 15, id >> 4, t);
  }
}

// ---------------------------------------------------------------------------
// pair_gt kernel (1280 blocks, 256 thr):
//  [0,256)     : GT GEMM tiles (longest chain first)
//  [256,1280)  : fused pair-MLP + softmax, Bi-reduced:
//    h = AjBi_init + [prod|adiff](K=48 pad 64) @ Wimg ; 12 MFMAs/tile.
// ---------------------------------------------------------------------------
#define FOFFB   0                       // 6*256*16 = 24576
#define LOGOFFB 24576                   // 512 f32 logits
#define ZJOFFB  (LOGOFFB + 2048)        // 24 f32
#define W2OFFB  (ZJOFFB + 96)           // 96 f32
#define AJOFFB  (W2OFFB + 384)          // 96 f32
#define REDOFFB (AJOFFB + 384)          // 8 f32
#define ZCOFFB  (REDOFFB + 32)          // 16B zero chunk
#define LDSB    32768                   // >= max(27536, GT ring 32768)

__global__ __launch_bounds__(256, 3) void pair_gt_kernel(
    const float* __restrict__ Zj, const float* __restrict__ Zi,
    const float* __restrict__ W1, const float* __restrict__ b1,
    const float* __restrict__ W2, const _Float16* __restrict__ Wimg,
    const float* __restrict__ mask, _Float16* __restrict__ probs,
    const _Float16* __restrict__ Wv1aT, const _Float16* __restrict__ HiH,
    _Float16* __restrict__ GT, const float* __restrict__ BiF) {
  __shared__ __attribute__((aligned(16))) char smem[LDSB];
  const int t = threadIdx.x;
  const int w = t >> 6, l = t & 63;
  const int lo = l & 15, hi = l >> 4;

  if (blockIdx.x < 256) {
    // ---------------- GT GEMM tile (256 thr, 4 waves, no split-K) ----------
    int id = blockIdx.x;               // 0..255
    int zb = id >> 7, rem = id & 127;
    int n0 = (rem & 7) * 64, m0 = (rem >> 3) * 64;
    const _Float16* Bb = HiH + (size_t)zb * S_ * HDIM;   // [512][1024]
    _Float16* GTb = GT + (size_t)zb * HDIM * S_;         // [1024][512]

    const int sr = (w << 4) + (l >> 2);
    const int sk = ((l & 3) ^ ((l >> 3) & 3)) << 3;
    const int mq = w >> 1, nq = w & 1;
    int offA[2], offB[2];
#pragma unroll
    for (int i = 0; i < 2; ++i) {
      int ra = mq * 32 + i * 16 + (l & 15);
      offA[i] = ra * 64 + (((l >> 4) ^ ((ra >> 1) & 3)) << 4);
      int rb = nq * 32 + i * 16 + (l & 15);
      offB[i] = 4096 + rb * 64 + (((l >> 4) ^ ((rb >> 1) & 3)) << 4);
    }
    f32x4 acc[2][2] = {};

    auto stage = [&](int tt) {
      char* buf = smem + (tt & 3) * 8192;
      int kg = (tt << 5) + sk;
      const _Float16* ga = Wv1aT + (size_t)(m0 + sr) * HDIM + kg;
      __builtin_amdgcn_global_load_lds(
          (const __attribute__((address_space(1))) void*)ga,
          (__attribute__((address_space(3))) void*)(buf + (w << 10)), 16, 0, 0);
      const _Float16* gb = Bb + (size_t)(n0 + sr) * HDIM + kg;
      __builtin_amdgcn_global_load_lds(
          (const __attribute__((address_space(1))) void*)gb,
          (__attribute__((address_space(3))) void*)(buf + 4096 + (w << 10)), 16, 0, 0);
    };
    stage(0); stage(1); stage(2);
    const int NT = HDIM >> 5;   // 32
    for (int tt = 0; tt < NT; ++tt) {
      if (tt + 2 < NT)      asm volatile("s_waitcnt vmcnt(4)" ::: "memory");
      else if (tt + 1 < NT) asm volatile("s_waitcnt vmcnt(2)" ::: "memory");
      else                  asm volatile("s_waitcnt vmcnt(0)" ::: "memory");
      __builtin_amdgcn_s_barrier();
      __builtin_amdgcn_sched_barrier(0);
      const char* buf = smem + (tt & 3) * 8192;
      half8 a0 = *(const half8*)(buf + offA[0]);
      half8 a1 = *(const half8*)(buf + offA[1]);
      half8 b0 = *(const half8*)(buf + offB[0]);
      half8 b1v = *(const half8*)(buf + offB[1]);
      acc[0][0] = __builtin_amdgcn_mfma_f32_16x16x32_f16(a0, b0, acc[0][0], 0, 0, 0);
      acc[0][1] = __builtin_amdgcn_mfma_f32_16x16x32_f16(a0, b1v, acc[0][1], 0, 0, 0);
      acc[1][0] = __builtin_amdgcn_mfma_f32_16x16x32_f16(a1, b0, acc[1][0], 0, 0, 0);
      acc[1][1] = __builtin_amdgcn_mfma_f32_16x16x32_f16(a1, b1v, acc[1][1], 0, 0, 0);
      if (tt + 3 < NT) stage(tt + 3);
    }
    const int lr = l & 15, lq = l >> 4;
#pragma unroll
    for (int mi = 0; mi < 2; ++mi)
#pragma unroll
      for (int ni = 0; ni < 2; ++ni) {
        int col = n0 + nq * 32 + ni * 16 + lr;
#pragma unroll
        for (int rg = 0; rg < 4; ++rg) {
          int row = m0 + mq * 32 + mi * 16 + lq * 4 + rg;
          GTb[(size_t)row * S_ + col] = (_Float16)acc[mi][ni][rg];
        }
      }
    return;
  }

  // ---------------- pair path (Bi-reduced) ----------------------------------
  const int rj = blockIdx.x - 256;
  const int b = rj >> 9;
  float* zjL    = (float*)(smem + ZJOFFB);
  float* W2s    = (float*)(smem + W2OFFB);
  float* ajL    = (float*)(smem + AJOFFB);
  float* logits = (float*)(smem + LOGOFFB);
  float* red    = (float*)(smem + REDOFFB);

  if (t < D_) zjL[t] = Zj[(size_t)rj * D_ + t];
  if (t < M_) {
    W2s[t] = W2[t];
    float aj = b1[t];
#pragma unroll
    for (int d = 0; d < D_; ++d)
      aj = fmaf(Zj[(size_t)rj * D_ + d], W1[d * M_ + t], aj);
    ajL[t] = aj;
  }
  if (t == 0) {
    half8 z = {};
    *(half8*)(smem + ZCOFFB) = z;
  }

  // W fragments: prod/adiff weights only (kc 0..5; kc 6,7 zero)
  half8 wf[6][2];
#pragma unroll
  for (int mh = 0; mh < 6; ++mh)
#pragma unroll
    for (int ks = 0; ks < 2; ++ks) {
      int kc = ks * 4 + hi;
      half8 v = {};
      if (kc < 6)
        v = *(const half8*)(Wimg + (size_t)(kc * 96 + mh * 16 + lo) * 8);
      wf[mh][ks] = v;
    }

  __syncthreads();   // zjL / W2s / ajL / zero chunk visible

  float w2r[6][4], ajr[6][4];
#pragma unroll
  for (int mh = 0; mh < 6; ++mh)
#pragma unroll
    for (int r = 0; r < 4; ++r) {
      w2r[mh][r] = W2s[mh * 16 + hi * 4 + r];
      ajr[mh][r] = ajL[mh * 16 + hi * 4 + r];
    }

  for (int p = 0; p < 2; ++p) {
    // ---- feature build: thread owns key i = p*256 + t; 6 chunks ----
    {
      int i = p * 256 + t;
      const float* zi = Zi + (size_t)(b * S_ + i) * D_;
      float ziv[D_];
#pragma unroll
      for (int q = 0; q < 6; ++q) {
        float4 v = ((const float4*)zi)[q];
        ziv[q * 4 + 0] = v.x; ziv[q * 4 + 1] = v.y;
        ziv[q * 4 + 2] = v.z; ziv[q * 4 + 3] = v.w;
      }
#pragma unroll
      for (int kc = 0; kc < 3; ++kc) {
        half8 v;
#pragma unroll
        for (int e = 0; e < 8; ++e) {
          int d = kc * 8 + e;
          v[e] = (_Float16)(zjL[d] * ziv[d]);
        }
        *(half8*)(smem + FOFFB + (kc * 256 + t) * 16) = v;
      }
#pragma unroll
      for (int kc = 0; kc < 3; ++kc) {
        half8 v;
#pragma unroll
        for (int e = 0; e < 8; ++e) {
          int d = kc * 8 + e;
          v[e] = (_Float16)fabsf(zjL[d] - ziv[d]);
        }
        *(half8*)(smem + FOFFB + ((kc + 3) * 256 + t) * 16) = v;
      }
    }
    __syncthreads();

    // ---- MFMA: wave w owns keys w*64 .. w*64+63 (4 N-tiles) ----
#pragma unroll
    for (int nt = 0; nt < 4; ++nt) {
      int i = p * 256 + w * 64 + nt * 16 + lo;   // this lane's key column
      half8 ff[2];
#pragma unroll
      for (int ks = 0; ks < 2; ++ks) {
        int kc = ks * 4 + hi;
        int off = (kc < 6) ? (FOFFB + (kc * 256 + w * 64 + nt * 16 + lo) * 16) : ZCOFFB;
        ff[ks] = *(const half8*)(smem + off);
      }
      f32x4 a6[6];
#pragma unroll
      for (int mh = 0; mh < 6; ++mh) {
        f32x4 bi4 = *(const f32x4*)(BiF + (size_t)(b * S_ + i) * M_ + mh * 16 + hi * 4);
#pragma unroll
        for (int r = 0; r < 4; ++r) a6[mh][r] = bi4[r] + ajr[mh][r];
      }
      __builtin_amdgcn_s_setprio(1);
#pragma unroll
      for (int ks = 0; ks < 2; ++ks)
#pragma unroll
        for (int mh = 0; mh < 6; ++mh)
          a6[mh] = __builtin_amdgcn_mfma_f32_16x16x32_f16(wf[mh][ks], ff[ks], a6[mh], 0, 0, 0);
      __builtin_amdgcn_s_setprio(0);
      float part = 0.f;
#pragma unroll
      for (int mh = 0; mh < 6; ++mh)
#pragma unroll
        for (int r = 0; r < 4; ++r)
          part = fmaf(fmaxf(a6[mh][r], 0.f), w2r[mh][r], part);
      part += __shfl_xor(part, 16);
      part += __shfl_xor(part, 32);
      if (hi == 0) logits[p * 256 + w * 64 + nt * 16 + lo] = part;
    }
    __syncthreads();
  }

  // ---- masked softmax over 512 keys (b2 dropped: shift-invariant) ----
  float m1 = mask[b * S_ + t], m2 = mask[b * S_ + t + 256];
  float lg1 = logits[t]       + (1.0f - m1) * (-3.40282347e38f);
  float lg2 = logits[t + 256] + (1.0f - m2) * (-3.40282347e38f);
  float mx = fmaxf(lg1, lg2);
#pragma unroll
  for (int off = 32; off > 0; off >>= 1) mx = fmaxf(mx, __shfl_xor(mx, off));
  if (l == 0) red[w] = mx;
  __syncthreads();
  float rmax = fmaxf(fmaxf(red[0], red[1]), fmaxf(red[2], red[3]));
  float e1 = __expf(lg1 - rmax);
  float e2 = __expf(lg2 - rmax);
  float s = e1 + e2;
#pragma unroll
  for (int off = 32; off > 0; off >>= 1) s += __shfl_xor(s, off);
  if (l == 0) red[4 + w] = s;
  __syncthreads();
  float inv = 1.0f / (red[4] + red[5] + red[6] + red[7]);
  probs[(size_t)rj * S_ + t]       = (_Float16)(e1 * inv);
  probs[(size_t)rj * S_ + t + 256] = (_Float16)(e2 * inv);
}

// ---------------------------------------------------------------------------
// fp16 MFMA GEMM, in-block split-K/2: 512 thr = 2 groups x 4 waves.
// Concat-K on BOTH operands (r12-proven).
// ---------------------------------------------------------------------------
template <bool SWZ, bool HASA1, bool HASB1, bool RELU, bool FINAL, bool OUTH>
__global__ __launch_bounds__(512) void mfma_gemm_kernel(
    const _Float16* __restrict__ A0, const _Float16* __restrict__ A1,
    const _Float16* __restrict__ B0, const _Float16* __restrict__ B1,
    const float* __restrict__ bias, const float* __restrict__ alpha_ptr,
    void* __restrict__ Cout, int M, int N, int K0, int K1,
    long aB0, long aB1, long bB0, long cB) {
  __shared__ __attribute__((aligned(16))) char smem[65536];
  const int t = threadIdx.x;
  const int w = t >> 6, l = t & 63;
  const int g = w >> 2, wq = w & 3;
  const int K = K0 + K1;
  const int KH = K >> 1;
  const int NT = KH >> 5;
  int n0, m0, zb;
  if (SWZ) {
    int s = (blockIdx.x & 7) * 32 + (blockIdx.x >> 3);  // XCD-chunked, bijective
    n0 = (s & 15) * 64; m0 = (s >> 4) * 64; zb = 0;
  } else {
    n0 = blockIdx.x * 64; m0 = blockIdx.y * 64; zb = blockIdx.z;
  }
  const _Float16* A0b = A0 + (size_t)zb * aB0;
  const _Float16* A1b = HASA1 ? (A1 + (size_t)zb * aB1) : nullptr;
  const _Float16* B0b = B0 + (size_t)zb * bB0;
  const int ldB0 = HASB1 ? K0 : K;
  char* gls = smem + (g << 15);

  const int sr = (wq << 4) + (l >> 2);
  const int sk = ((l & 3) ^ ((l >> 3) & 3)) << 3;

  const int mq = wq >> 1, nq = wq & 1;
  int offA[2], offB[2];
#pragma unroll
  for (int i = 0; i < 2; ++i) {
    int ra = mq * 32 + i * 16 + (l & 15);
    offA[i] = ra * 64 + (((l >> 4) ^ ((ra >> 1) & 3)) << 4);
    int rb = nq * 32 + i * 16 + (l & 15);
    offB[i] = 4096 + rb * 64 + (((l >> 4) ^ ((rb >> 1) & 3)) << 4);
  }

  f32x4 acc[2][2] = {};

  auto stage = [&](int tt) {
    char* buf = gls + (tt & 3) * 8192;
    int kg = g * KH + (tt << 5) + sk;
    const _Float16* ga;
    if (HASA1 && kg >= K0) ga = A1b + (size_t)(m0 + sr) * K1 + (kg - K0);
    else                   ga = A0b + (size_t)(m0 + sr) * K0 + kg;
    __builtin_amdgcn_global_load_lds(
        (const __attribute__((address_space(1))) void*)ga,
        (__attribute__((address_space(3))) void*)(buf + (wq << 10)), 16, 0, 0);
    const _Float16* gb;
    if (HASB1 && kg >= K0) gb = B1 + (size_t)(n0 + sr) * K1 + (kg - K0);
    else                   gb = B0b + (size_t)(n0 + sr) * ldB0 + kg;
    __builtin_amdgcn_global_load_lds(
        (const __attribute__((address_space(1))) void*)gb,
        (__attribute__((address_space(3))) void*)(buf + 4096 + (wq << 10)), 16, 0, 0);
  };

  stage(0);
  stage(1);
  stage(2);

  for (int tt = 0; tt < NT; ++tt) {
    if (tt + 2 < NT)      asm volatile("s_waitcnt vmcnt(4)" ::: "memory");
    else if (tt + 1 < NT) asm volatile("s_waitcnt vmcnt(2)" ::: "memory");
    else                  asm volatile("s_waitcnt vmcnt(0)" ::: "memory");
    __builtin_amdgcn_s_barrier();
    __builtin_amdgcn_sched_barrier(0);
    const char* buf = gls + (tt & 3) * 8192;
    half8 a0 = *(const half8*)(buf + offA[0]);
    half8 a1 = *(const half8*)(buf + offA[1]);
    half8 b0 = *(const half8*)(buf + offB[0]);
    half8 b1v = *(const half8*)(buf + offB[1]);
    acc[0][0] = __builtin_amdgcn_mfma_f32_16x16x32_f16(a0, b0, acc[0][0], 0, 0, 0);
    acc[0][1] = __builtin_amdgcn_mfma_f32_16x16x32_f16(a0, b1v, acc[0][1], 0, 0, 0);
    acc[1][0] = __builtin_amdgcn_mfma_f32_16x16x32_f16(a1, b0, acc[1][0], 0, 0, 0);
    acc[1][1] = __builtin_amdgcn_mfma_f32_16x16x32_f16(a1, b1v, acc[1][1], 0, 0, 0);
    if (tt + 3 < NT) stage(tt + 3);
  }

  // cross-group K reduction through LDS (overlays group-0 ring, now dead)
  const int lr = l & 15, lq = l >> 4;
  float* redm = (float*)smem;   // [64][68]
  __syncthreads();
  if (g == 1) {
#pragma unroll
    for (int mi = 0; mi < 2; ++mi)
#pragma unroll
      for (int ni = 0; ni < 2; ++ni)
#pragma unroll
        for (int rg = 0; rg < 4; ++rg)
          redm[(mq * 32 + mi * 16 + lq * 4 + rg) * 68 + nq * 32 + ni * 16 + lr] =
              acc[mi][ni][rg];
  }
  __syncthreads();
  if (g == 0) {
    const float alpha = FINAL ? *alpha_ptr : 1.0f;
    const size_t cbase = (size_t)zb * cB;
#pragma unroll
    for (int mi = 0; mi < 2; ++mi)
#pragma unroll
      for (int ni = 0; ni < 2; ++ni) {
        int col = n0 + nq * 32 + ni * 16 + lr;
        float bv = bias ? bias[col] : 0.0f;
#pragma unroll
        for (int rg = 0; rg < 4; ++rg) {
          int row = m0 + mq * 32 + mi * 16 + lq * 4 + rg;
          float x = acc[mi][ni][rg] +
                    redm[(mq * 32 + mi * 16 + lq * 4 + rg) * 68 + nq * 32 + ni * 16 + lr] +
                    bv;
          if (RELU) x = fmaxf(x, 0.f);
          if (FINAL) x *= alpha;
          if (OUTH)
            ((_Float16*)Cout)[cbase + (size_t)row * N + col] = (_Float16)x;
          else
            ((float*)Cout)[cbase + (size_t)row * N + col] = x;
        }
      }
  }
}

// ---------------------------------------------------------------------------
extern "C" void kernel_launch(void* const* d_in, const int* in_sizes, int n_in,
                              void* d_out, int out_size, void* d_ws, size_t ws_size,
                              hipStream_t stream) {
  const float* Hj   = (const float*)d_in[0];
  const float* Hi   = (const float*)d_in[1];
  const float* mask = (const float*)d_in[2];
  const float* pj   = (const float*)d_in[3];
  const float* pi   = (const float*)d_in[4];
  const float* W1   = (const float*)d_in[5];
  const float* b1   = (const float*)d_in[6];
  const float* W2   = (const float*)d_in[7];
  // d_in[8] = b2: uniform over keys -> softmax invariant, unused
  const float* Wv1  = (const float*)d_in[9];
  const float* bv1  = (const float*)d_in[10];
  const float* Wv2  = (const float*)d_in[11];
  const float* bv2  = (const float*)d_in[12];
  const float* alpha = (const float*)d_in[13];

  char* w = (char*)d_ws;
  float* Zj  = (float*)w;            w += (size_t)ROWS * D_ * 4;
  float* Zi  = (float*)w;            w += (size_t)ROWS * D_ * 4;
  float* BiF = (float*)w;            w += (size_t)ROWS * M_ * 4;
  _Float16* Wimg   = (_Float16*)w;   w += (size_t)1024 * 16;
  _Float16* probsH = (_Float16*)w;   w += (size_t)B_ * S_ * S_ * 2;
  _Float16* HjH    = (_Float16*)w;   w += (size_t)ROWS * HDIM * 2;
  _Float16* HiH    = (_Float16*)w;   w += (size_t)ROWS * HDIM * 2;
  _Float16* Wv1aT  = (_Float16*)w;   w += (size_t)HDIM * HDIM * 2;
  _Float16* Wv1bT  = (_Float16*)w;   w += (size_t)HDIM * HDIM * 2;
  _Float16* Wv2T   = (_Float16*)w;   w += (size_t)HDIM * HDIM * 2;
  _Float16* GT     = (_Float16*)w;   w += (size_t)B_ * HDIM * S_ * 2;
  _Float16* hidH   = (_Float16*)w;   w += (size_t)ROWS * HDIM * 2;
  float* out = (float*)d_out;

  // 1) prep: projections (+fp16 images, +Bi), weight images, transposes
  prep_kernel<<<804, 256, 0, stream>>>(Hj, Hi, pj, pi, W1, Wv1, Wv2,
                                       HjH, HiH, Wv1aT, Wv1bT, Wv2T, Wimg,
                                       Zj, Zi, BiF);

  // 2) GT (256, longest chain first) + pair-MLP/softmax (1024, Bi-reduced)
  pair_gt_kernel<<<ROWS + 256, 256, 0, stream>>>(Zj, Zi, W1, b1, W2, Wimg,
                                                 mask, probsH, Wv1aT, HiH, GT,
                                                 BiF);

  // 3) hidden = relu([probs|HjH] @ [GT_b; Wv1bT]^T + bv1)  (K=1536, z=2)
  mfma_gemm_kernel<false, true, true, true, false, true>
      <<<dim3(16, 8, 2), 512, 0, stream>>>(
      probsH, HjH, GT, Wv1bT, bv1, nullptr, hidH,
      S_, HDIM, S_, HDIM,
      (long)S_ * S_, (long)S_ * HDIM, (long)HDIM * S_, (long)S_ * HDIM);

  // 4) out = alpha * (hidden @ Wv2 + bv2)   (K=1024, 256 blocks, XCD swizzle)
  mfma_gemm_kernel<true, false, false, false, true, false>
      <<<dim3(256), 512, 0, stream>>>(
      hidH, nullptr, Wv2T, nullptr, bv2, alpha, out,
      ROWS, HDIM, HDIM, 0, 0, 0, 0, 0);
}

// Round 16
// 64.832 us; speedup vs baseline: 1.3771x; 1.3771x over previous
//
#include <hip/hip_runtime.h>
#include <math.h>

#define B_    2
#define S_    512
#define HDIM  1024
#define D_    24      // proj dim
#define M_    96      // pair-MLP hidden
#define ROWS  (B_*S_) // 1024

typedef _Float16 half8 __attribute__((ext_vector_type(8)));
typedef float    f32x4 __attribute__((ext_vector_type(4)));
typedef unsigned short ushort8 __attribute__((ext_vector_type(8)));

// ---------------------------------------------------------------------------
// cache-based 64x64 fp32->fp16 transpose, 256 threads (no LDS)
// ---------------------------------------------------------------------------
__device__ __forceinline__ void transpose_tile64_cache(
    const float* __restrict__ in, _Float16* __restrict__ out,
    int R, int C, int xt, int yt, int t) {
  int R0 = yt * 64, C0 = xt * 64;
  int c = t >> 2, rq = (t & 3) * 16;
  _Float16 o[16];
  const float* src = in + (size_t)(R0 + rq) * C + C0 + c;
#pragma unroll
  for (int e = 0; e < 16; ++e) o[e] = (_Float16)src[(size_t)e * C];
  _Float16* dst = out + (size_t)(C0 + c) * R + R0 + rq;
  *(ushort8*)dst = *(ushort8*)o;
  *(ushort8*)(dst + 8) = *(ushort8*)&o[8];
}

// ---------------------------------------------------------------------------
// MFMA projection, 64 rows per block (4 waves x 16 rows). P ([1024][24] fp32)
// staged inline into LDS fp16 B-fragments in two 16-step phases (32KB).
// Emits fp16 image of H rows (free: same bytes already in registers).
// ---------------------------------------------------------------------------
__device__ __forceinline__ void proj_mfma64(
    const float* __restrict__ H, const float* __restrict__ P,
    float* __restrict__ Z, _Float16* __restrict__ Himg,
    int r0, char* smem, int t) {
  const int w = t >> 6, l = t & 63;
  const int lo = l & 15, hi = l >> 4;
  const int row = r0 + w * 16 + lo;
  const float* hrow = H + (size_t)row * HDIM;
  f32x4 acc0 = {}, acc1 = {};

  for (int ph = 0; ph < 2; ++ph) {
    if (ph) __syncthreads();   // all waves done reading phase-0 fragments
    for (int q = 0; q < 8; ++q) {
      int s = t + q * 256;
      int slo = s & 15, shi = (s >> 4) & 3, snt = (s >> 6) & 1, sst = s >> 7;
      int d = snt * 16 + slo;
      half8 v = {};
      if (d < D_) {
        int k = (ph * 16 + sst) * 32 + shi * 8;
#pragma unroll
        for (int e = 0; e < 8; ++e)
          v[e] = (_Float16)P[(size_t)(k + e) * D_ + d];
      }
      *(half8*)(smem + s * 16) = v;
    }
    __syncthreads();

    for (int st = 0; st < 16; ++st) {
      int step = ph * 16 + st;
      const float* src = hrow + step * 32 + hi * 8;
      float4 v0 = *(const float4*)src;
      float4 v1 = *(const float4*)(src + 4);
      half8 a8;
      a8[0] = (_Float16)v0.x; a8[1] = (_Float16)v0.y;
      a8[2] = (_Float16)v0.z; a8[3] = (_Float16)v0.w;
      a8[4] = (_Float16)v1.x; a8[5] = (_Float16)v1.y;
      a8[6] = (_Float16)v1.z; a8[7] = (_Float16)v1.w;
      *(half8*)(Himg + (size_t)row * HDIM + step * 32 + hi * 8) = a8;
      half8 b0 = *(const half8*)(smem + ((st * 2 + 0) * 64 + l) * 16);
      half8 b1 = *(const half8*)(smem + ((st * 2 + 1) * 64 + l) * 16);
      acc0 = __builtin_amdgcn_mfma_f32_16x16x32_f16(a8, b0, acc0, 0, 0, 0);
      acc1 = __builtin_amdgcn_mfma_f32_16x16x32_f16(a8, b1, acc1, 0, 0, 0);
    }
  }
#pragma unroll
  for (int rg = 0; rg < 4; ++rg) {
    int zr = r0 + w * 16 + hi * 4 + rg;
    Z[(size_t)zr * D_ + lo] = acc0[rg];
    if (lo < 8) Z[(size_t)zr * D_ + 16 + lo] = acc1[rg];
  }
}

// ---------------------------------------------------------------------------
// Merged prep kernel: blockIdx ranges
//  [0,16)    : proj Zj + HjH emit, 64 rows per block
//  [16,32)   : proj Zi + HiH emit
//  [32,36)   : Wimg
//  [36,292)  : Wv1aT tiles (transpose of Wv1 rows 0..1023)
//  [292,548) : Wv1bT tiles (transpose of Wv1 rows 1024..2047)
//  [548,804) : Wv2T tiles
// ---------------------------------------------------------------------------
__global__ __launch_bounds__(256) void prep_kernel(
    const float* __restrict__ Hj, const float* __restrict__ Hi,
    const float* __restrict__ pj, const float* __restrict__ pi,
    const float* __restrict__ W1, const float* __restrict__ Wv1,
    const float* __restrict__ Wv2,
    _Float16* __restrict__ HjH, _Float16* __restrict__ HiH,
    _Float16* __restrict__ Wv1aT, _Float16* __restrict__ Wv1bT,
    _Float16* __restrict__ Wv2T, _Float16* __restrict__ Wimg,
    float* __restrict__ Zj, float* __restrict__ Zi) {
  __shared__ __attribute__((aligned(16))) char smem[32768];
  const int bid = blockIdx.x;
  const int t = threadIdx.x;

  if (bid < 16) {
    proj_mfma64(Hj, pj, Zj, HjH, bid * 64, smem, t);
  } else if (bid < 32) {
    proj_mfma64(Hi, pi, Zi, HiH, (bid - 16) * 64, smem, t);
  } else if (bid < 36) {
    int c = (bid - 32) * 256 + t;   // 0..1023
    half8 v = {};
    if (c < 864) {
      int kc = c / 96, m = c - kc * 96;
#pragma unroll
      for (int e = 0; e < 8; ++e)
        v[e] = (_Float16)W1[(24 + kc * 8 + e) * M_ + m];
    }
    *(half8*)(Wimg + (size_t)c * 8) = v;
  } else if (bid < 292) {
    int id = bid - 36;                 // 16 x 16 tiles
    transpose_tile64_cache(Wv1, Wv1aT, HDIM, HDIM, id & 15, id >> 4, t);
  } else if (bid < 548) {
    int id = bid - 292;
    transpose_tile64_cache(Wv1 + (size_t)HDIM * HDIM, Wv1bT, HDIM, HDIM,
                           id & 15, id >> 4, t);
  } else {
    int id = bid - 548;
    transpose_tile64_cache(Wv2, Wv2T, HDIM, HDIM, id & 15, id >> 4, t);
  }
}

// ---------------------------------------------------------------------------
// Fused pair-MLP + softmax (blocks 0..1023) AND GT GEMM (blocks 1024..1279).
// GT_b = Wv1aT @ HiH_b^T  (M=1024, N=512, K=1024) — independent of pair.
// ---------------------------------------------------------------------------
#define FOFFB   0                       // 10*256*16 = 40960
#define LOGOFFB 40960                   // 512 f32 logits
#define ZJOFFB  (LOGOFFB + 2048)        // 24 f32
#define W2OFFB  (ZJOFFB + 96)           // 96 f32
#define AJOFFB  (W2OFFB + 384)          // 96 f32
#define REDOFFB (AJOFFB + 384)          // 8 f32
#define ZCOFFB  (REDOFFB + 32)          // 16B zero chunk
#define LDSB    (ZCOFFB + 16)           // 43920

__global__ __launch_bounds__(256, 3) void pair_gt_kernel(
    const float* __restrict__ Zj, const float* __restrict__ Zi,
    const float* __restrict__ W1, const float* __restrict__ b1,
    const float* __restrict__ W2, const _Float16* __restrict__ Wimg,
    const float* __restrict__ mask, _Float16* __restrict__ probs,
    const _Float16* __restrict__ Wv1aT, const _Float16* __restrict__ HiH,
    _Float16* __restrict__ GT) {
  __shared__ __attribute__((aligned(16))) char smem[LDSB];
  const int t = threadIdx.x;
  const int w = t >> 6, l = t & 63;
  const int lo = l & 15, hi = l >> 4;

  if (blockIdx.x >= ROWS) {
    // ---------------- GT GEMM tile (256 thr, 4 waves, no split-K) ----------
    int id = blockIdx.x - ROWS;        // 0..255
    int zb = id >> 7, rem = id & 127;
    int n0 = (rem & 7) * 64, m0 = (rem >> 3) * 64;
    const _Float16* Bb = HiH + (size_t)zb * S_ * HDIM;   // [512][1024]
    _Float16* GTb = GT + (size_t)zb * HDIM * S_;         // [1024][512]

    const int sr = (w << 4) + (l >> 2);
    const int sk = ((l & 3) ^ ((l >> 3) & 3)) << 3;
    const int mq = w >> 1, nq = w & 1;
    int offA[2], offB[2];
#pragma unroll
    for (int i = 0; i < 2; ++i) {
      int ra = mq * 32 + i * 16 + (l & 15);
      offA[i] = ra * 64 + (((l >> 4) ^ ((ra >> 1) & 3)) << 4);
      int rb = nq * 32 + i * 16 + (l & 15);
      offB[i] = 4096 + rb * 64 + (((l >> 4) ^ ((rb >> 1) & 3)) << 4);
    }
    f32x4 acc[2][2] = {};

    auto stage = [&](int tt) {
      char* buf = smem + (tt & 3) * 8192;
      int kg = (tt << 5) + sk;
      const _Float16* ga = Wv1aT + (size_t)(m0 + sr) * HDIM + kg;
      __builtin_amdgcn_global_load_lds(
          (const __attribute__((address_space(1))) void*)ga,
          (__attribute__((address_space(3))) void*)(buf + (w << 10)), 16, 0, 0);
      const _Float16* gb = Bb + (size_t)(n0 + sr) * HDIM + kg;
      __builtin_amdgcn_global_load_lds(
          (const __attribute__((address_space(1))) void*)gb,
          (__attribute__((address_space(3))) void*)(buf + 4096 + (w << 10)), 16, 0, 0);
    };
    stage(0); stage(1); stage(2);
    const int NT = HDIM >> 5;   // 32
    for (int tt = 0; tt < NT; ++tt) {
      if (tt + 2 < NT)      asm volatile("s_waitcnt vmcnt(4)" ::: "memory");
      else if (tt + 1 < NT) asm volatile("s_waitcnt vmcnt(2)" ::: "memory");
      else                  asm volatile("s_waitcnt vmcnt(0)" ::: "memory");
      __builtin_amdgcn_s_barrier();
      __builtin_amdgcn_sched_barrier(0);
      const char* buf = smem + (tt & 3) * 8192;
      half8 a0 = *(const half8*)(buf + offA[0]);
      half8 a1 = *(const half8*)(buf + offA[1]);
      half8 b0 = *(const half8*)(buf + offB[0]);
      half8 b1v = *(const half8*)(buf + offB[1]);
      acc[0][0] = __builtin_amdgcn_mfma_f32_16x16x32_f16(a0, b0, acc[0][0], 0, 0, 0);
      acc[0][1] = __builtin_amdgcn_mfma_f32_16x16x32_f16(a0, b1v, acc[0][1], 0, 0, 0);
      acc[1][0] = __builtin_amdgcn_mfma_f32_16x16x32_f16(a1, b0, acc[1][0], 0, 0, 0);
      acc[1][1] = __builtin_amdgcn_mfma_f32_16x16x32_f16(a1, b1v, acc[1][1], 0, 0, 0);
      if (tt + 3 < NT) stage(tt + 3);
    }
    const int lr = l & 15, lq = l >> 4;
#pragma unroll
    for (int mi = 0; mi < 2; ++mi)
#pragma unroll
      for (int ni = 0; ni < 2; ++ni) {
        int col = n0 + nq * 32 + ni * 16 + lr;
#pragma unroll
        for (int rg = 0; rg < 4; ++rg) {
          int row = m0 + mq * 32 + mi * 16 + lq * 4 + rg;
          GTb[(size_t)row * S_ + col] = (_Float16)acc[mi][ni][rg];
        }
      }
    return;
  }

  // ---------------- pair path (r11-proven) ---------------------------------
  const int rj = blockIdx.x;
  const int b = rj >> 9;
  float* zjL    = (float*)(smem + ZJOFFB);
  float* W2s    = (float*)(smem + W2OFFB);
  float* ajL    = (float*)(smem + AJOFFB);
  float* logits = (float*)(smem + LOGOFFB);
  float* red    = (float*)(smem + REDOFFB);

  if (t < D_) zjL[t] = Zj[(size_t)rj * D_ + t];
  if (t < M_) {
    W2s[t] = W2[t];
    float aj = b1[t];
#pragma unroll
    for (int d = 0; d < D_; ++d)
      aj = fmaf(Zj[(size_t)rj * D_ + d], W1[d * M_ + t], aj);
    ajL[t] = aj;
  }
  if (t == 0) {
    half8 z = {};
    *(half8*)(smem + ZCOFFB) = z;
  }

  half8 wf[6][3];
#pragma unroll
  for (int mh = 0; mh < 6; ++mh)
#pragma unroll
    for (int ks = 0; ks < 3; ++ks) {
      int kc = ks * 4 + hi;
      half8 v = {};
      if (kc < 10)
        v = *(const half8*)(Wimg + (size_t)(kc * 96 + mh * 16 + lo) * 8);
      wf[mh][ks] = v;
    }

  __syncthreads();

  if (hi == 1) {
#pragma unroll
    for (int mh = 0; mh < 6; ++mh)
      wf[mh][2][0] = (_Float16)ajL[mh * 16 + lo];
  }
  float w2r[6][4];
#pragma unroll
  for (int mh = 0; mh < 6; ++mh)
#pragma unroll
    for (int r = 0; r < 4; ++r) w2r[mh][r] = W2s[mh * 16 + hi * 4 + r];

  for (int p = 0; p < 2; ++p) {
    {
      int i = p * 256 + t;
      const float* zi = Zi + (size_t)(b * S_ + i) * D_;
      float ziv[D_];
#pragma unroll
      for (int q = 0; q < 6; ++q) {
        float4 v = ((const float4*)zi)[q];
        ziv[q * 4 + 0] = v.x; ziv[q * 4 + 1] = v.y;
        ziv[q * 4 + 2] = v.z; ziv[q * 4 + 3] = v.w;
      }
#pragma unroll
      for (int kc = 0; kc < 3; ++kc) {
        half8 v;
#pragma unroll
        for (int e = 0; e < 8; ++e) v[e] = (_Float16)ziv[kc * 8 + e];
        *(half8*)(smem + FOFFB + (kc * 256 + t) * 16) = v;
      }
#pragma unroll
      for (int kc = 0; kc < 3; ++kc) {
        half8 v;
#pragma unroll
        for (int e = 0; e < 8; ++e) {
          int d = kc * 8 + e;
          v[e] = (_Float16)(zjL[d] * ziv[d]);
        }
        *(half8*)(smem + FOFFB + ((kc + 3) * 256 + t) * 16) = v;
      }
#pragma unroll
      for (int kc = 0; kc < 3; ++kc) {
        half8 v;
#pragma unroll
        for (int e = 0; e < 8; ++e) {
          int d = kc * 8 + e;
          v[e] = (_Float16)fabsf(zjL[d] - ziv[d]);
        }
        *(half8*)(smem + FOFFB + ((kc + 6) * 256 + t) * 16) = v;
      }
      if (p == 0) {
        half8 v = {};
        v[0] = (_Float16)1.0f;
        *(half8*)(smem + FOFFB + (9 * 256 + t) * 16) = v;
      }
    }
    __syncthreads();

#pragma unroll
    for (int nt = 0; nt < 4; ++nt) {
      half8 ff[3];
#pragma unroll
      for (int ks = 0; ks < 3; ++ks) {
        int kc = ks * 4 + hi;
        int off = (kc < 10) ? (FOFFB + (kc * 256 + w * 64 + nt * 16 + lo) * 16) : ZCOFFB;
        ff[ks] = *(const half8*)(smem + off);
      }
      f32x4 a6[6] = {};
      __builtin_amdgcn_s_setprio(1);
#pragma unroll
      for (int ks = 0; ks < 3; ++ks)
#pragma unroll
        for (int mh = 0; mh < 6; ++mh)
          a6[mh] = __builtin_amdgcn_mfma_f32_16x16x32_f16(wf[mh][ks], ff[ks], a6[mh], 0, 0, 0);
      __builtin_amdgcn_s_setprio(0);
      float part = 0.f;
#pragma unroll
      for (int mh = 0; mh < 6; ++mh)
#pragma unroll
        for (int r = 0; r < 4; ++r)
          part = fmaf(fmaxf(a6[mh][r], 0.f), w2r[mh][r], part);
      part += __shfl_xor(part, 16);
      part += __shfl_xor(part, 32);
      if (hi == 0) logits[p * 256 + w * 64 + nt * 16 + lo] = part;
    }
    __syncthreads();
  }

  float m1 = mask[b * S_ + t], m2 = mask[b * S_ + t + 256];
  float lg1 = logits[t]       + (1.0f - m1) * (-3.40282347e38f);
  float lg2 = logits[t + 256] + (1.0f - m2) * (-3.40282347e38f);
  float mx = fmaxf(lg1, lg2);
#pragma unroll
  for (int off = 32; off > 0; off >>= 1) mx = fmaxf(mx, __shfl_xor(mx, off));
  if (l == 0) red[w] = mx;
  __syncthreads();
  float rmax = fmaxf(fmaxf(red[0], red[1]), fmaxf(red[2], red[3]));
  float e1 = __expf(lg1 - rmax);
  float e2 = __expf(lg2 - rmax);
  float s = e1 + e2;
#pragma unroll
  for (int off = 32; off > 0; off >>= 1) s += __shfl_xor(s, off);
  if (l == 0) red[4 + w] = s;
  __syncthreads();
  float inv = 1.0f / (red[4] + red[5] + red[6] + red[7]);
  probs[(size_t)rj * S_ + t]       = (_Float16)(e1 * inv);
  probs[(size_t)rj * S_ + t + 256] = (_Float16)(e2 * inv);
}

// ---------------------------------------------------------------------------
// fp16 MFMA GEMM, in-block split-K/2: 512 thr = 2 groups x 4 waves.
// Concat-K on BOTH operands: A = [A0|A1], B rows = [B0_b ; B1] split at K0.
// ---------------------------------------------------------------------------
template <bool SWZ, bool HASA1, bool HASB1, bool RELU, bool FINAL, bool OUTH>
__global__ __launch_bounds__(512) void mfma_gemm_kernel(
    const _Float16* __restrict__ A0, const _Float16* __restrict__ A1,
    const _Float16* __restrict__ B0, const _Float16* __restrict__ B1,
    const float* __restrict__ bias, const float* __restrict__ alpha_ptr,
    void* __restrict__ Cout, int M, int N, int K0, int K1,
    long aB0, long aB1, long bB0, long cB) {
  __shared__ __attribute__((aligned(16))) char smem[65536];
  const int t = threadIdx.x;
  const int w = t >> 6, l = t & 63;
  const int g = w >> 2, wq = w & 3;
  const int K = K0 + K1;
  const int KH = K >> 1;
  const int NT = KH >> 5;
  int n0, m0, zb;
  if (SWZ) {
    int s = (blockIdx.x & 7) * 32 + (blockIdx.x >> 3);  // XCD-chunked, bijective
    n0 = (s & 15) * 64; m0 = (s >> 4) * 64; zb = 0;
  } else {
    n0 = blockIdx.x * 64; m0 = blockIdx.y * 64; zb = blockIdx.z;
  }
  const _Float16* A0b = A0 + (size_t)zb * aB0;
  const _Float16* A1b = HASA1 ? (A1 + (size_t)zb * aB1) : nullptr;
  const _Float16* B0b = B0 + (size_t)zb * bB0;
  const int ldB0 = HASB1 ? K0 : K;
  char* gls = smem + (g << 15);

  const int sr = (wq << 4) + (l >> 2);
  const int sk = ((l & 3) ^ ((l >> 3) & 3)) << 3;

  const int mq = wq >> 1, nq = wq & 1;
  int offA[2], offB[2];
#pragma unroll
  for (int i = 0; i < 2; ++i) {
    int ra = mq * 32 + i * 16 + (l & 15);
    offA[i] = ra * 64 + (((l >> 4) ^ ((ra >> 1) & 3)) << 4);
    int rb = nq * 32 + i * 16 + (l & 15);
    offB[i] = 4096 + rb * 64 + (((l >> 4) ^ ((rb >> 1) & 3)) << 4);
  }

  f32x4 acc[2][2] = {};

  auto stage = [&](int tt) {
    char* buf = gls + (tt & 3) * 8192;
    int kg = g * KH + (tt << 5) + sk;
    const _Float16* ga;
    if (HASA1 && kg >= K0) ga = A1b + (size_t)(m0 + sr) * K1 + (kg - K0);
    else                   ga = A0b + (size_t)(m0 + sr) * K0 + kg;
    __builtin_amdgcn_global_load_lds(
        (const __attribute__((address_space(1))) void*)ga,
        (__attribute__((address_space(3))) void*)(buf + (wq << 10)), 16, 0, 0);
    const _Float16* gb;
    if (HASB1 && kg >= K0) gb = B1 + (size_t)(n0 + sr) * K1 + (kg - K0);
    else                   gb = B0b + (size_t)(n0 + sr) * ldB0 + kg;
    __builtin_amdgcn_global_load_lds(
        (const __attribute__((address_space(1))) void*)gb,
        (__attribute__((address_space(3))) void*)(buf + 4096 + (wq << 10)), 16, 0, 0);
  };

  stage(0);
  stage(1);
  stage(2);

  for (int tt = 0; tt < NT; ++tt) {
    if (tt + 2 < NT)      asm volatile("s_waitcnt vmcnt(4)" ::: "memory");
    else if (tt + 1 < NT) asm volatile("s_waitcnt vmcnt(2)" ::: "memory");
    else                  asm volatile("s_waitcnt vmcnt(0)" ::: "memory");
    __builtin_amdgcn_s_barrier();
    __builtin_amdgcn_sched_barrier(0);
    const char* buf = gls + (tt & 3) * 8192;
    half8 a0 = *(const half8*)(buf + offA[0]);
    half8 a1 = *(const half8*)(buf + offA[1]);
    half8 b0 = *(const half8*)(buf + offB[0]);
    half8 b1v = *(const half8*)(buf + offB[1]);
    acc[0][0] = __builtin_amdgcn_mfma_f32_16x16x32_f16(a0, b0, acc[0][0], 0, 0, 0);
    acc[0][1] = __builtin_amdgcn_mfma_f32_16x16x32_f16(a0, b1v, acc[0][1], 0, 0, 0);
    acc[1][0] = __builtin_amdgcn_mfma_f32_16x16x32_f16(a1, b0, acc[1][0], 0, 0, 0);
    acc[1][1] = __builtin_amdgcn_mfma_f32_16x16x32_f16(a1, b1v, acc[1][1], 0, 0, 0);
    if (tt + 3 < NT) stage(tt + 3);
  }

  // cross-group K reduction through LDS (overlays group-0 ring, now dead)
  const int lr = l & 15, lq = l >> 4;
  float* redm = (float*)smem;   // [64][68]
  __syncthreads();
  if (g == 1) {
#pragma unroll
    for (int mi = 0; mi < 2; ++mi)
#pragma unroll
      for (int ni = 0; ni < 2; ++ni)
#pragma unroll
        for (int rg = 0; rg < 4; ++rg)
          redm[(mq * 32 + mi * 16 + lq * 4 + rg) * 68 + nq * 32 + ni * 16 + lr] =
              acc[mi][ni][rg];
  }
  __syncthreads();
  if (g == 0) {
    const float alpha = FINAL ? *alpha_ptr : 1.0f;
    const size_t cbase = (size_t)zb * cB;
#pragma unroll
    for (int mi = 0; mi < 2; ++mi)
#pragma unroll
      for (int ni = 0; ni < 2; ++ni) {
        int col = n0 + nq * 32 + ni * 16 + lr;
        float bv = bias ? bias[col] : 0.0f;
#pragma unroll
        for (int rg = 0; rg < 4; ++rg) {
          int row = m0 + mq * 32 + mi * 16 + lq * 4 + rg;
          float x = acc[mi][ni][rg] +
                    redm[(mq * 32 + mi * 16 + lq * 4 + rg) * 68 + nq * 32 + ni * 16 + lr] +
                    bv;
          if (RELU) x = fmaxf(x, 0.f);
          if (FINAL) x *= alpha;
          if (OUTH)
            ((_Float16*)Cout)[cbase + (size_t)row * N + col] = (_Float16)x;
          else
            ((float*)Cout)[cbase + (size_t)row * N + col] = x;
        }
      }
  }
}

// ---------------------------------------------------------------------------
extern "C" void kernel_launch(void* const* d_in, const int* in_sizes, int n_in,
                              void* d_out, int out_size, void* d_ws, size_t ws_size,
                              hipStream_t stream) {
  const float* Hj   = (const float*)d_in[0];
  const float* Hi   = (const float*)d_in[1];
  const float* mask = (const float*)d_in[2];
  const float* pj   = (const float*)d_in[3];
  const float* pi   = (const float*)d_in[4];
  const float* W1   = (const float*)d_in[5];
  const float* b1   = (const float*)d_in[6];
  const float* W2   = (const float*)d_in[7];
  // d_in[8] = b2: uniform over keys -> softmax invariant, unused
  const float* Wv1  = (const float*)d_in[9];
  const float* bv1  = (const float*)d_in[10];
  const float* Wv2  = (const float*)d_in[11];
  const float* bv2  = (const float*)d_in[12];
  const float* alpha = (const float*)d_in[13];

  char* w = (char*)d_ws;
  float* Zj  = (float*)w;            w += (size_t)ROWS * D_ * 4;
  float* Zi  = (float*)w;            w += (size_t)ROWS * D_ * 4;
  _Float16* Wimg   = (_Float16*)w;   w += (size_t)1024 * 16;
  _Float16* probsH = (_Float16*)w;   w += (size_t)B_ * S_ * S_ * 2;
  _Float16* HjH    = (_Float16*)w;   w += (size_t)ROWS * HDIM * 2;
  _Float16* HiH    = (_Float16*)w;   w += (size_t)ROWS * HDIM * 2;
  _Float16* Wv1aT  = (_Float16*)w;   w += (size_t)HDIM * HDIM * 2;
  _Float16* Wv1bT  = (_Float16*)w;   w += (size_t)HDIM * HDIM * 2;
  _Float16* Wv2T   = (_Float16*)w;   w += (size_t)HDIM * HDIM * 2;
  _Float16* GT     = (_Float16*)w;   w += (size_t)B_ * HDIM * S_ * 2;
  _Float16* hidH   = (_Float16*)w;   w += (size_t)ROWS * HDIM * 2;
  float* out = (float*)d_out;

  // 1) prep: projections (+fp16 images), weight images, weight transposes
  prep_kernel<<<804, 256, 0, stream>>>(Hj, Hi, pj, pi, W1, Wv1, Wv2,
                                       HjH, HiH, Wv1aT, Wv1bT, Wv2T, Wimg,
                                       Zj, Zi);

  // 2) pair-MLP+softmax (1024 blocks) + GT = Wv1aT @ HiH^T (256 blocks)
  pair_gt_kernel<<<ROWS + 256, 256, 0, stream>>>(Zj, Zi, W1, b1, W2, Wimg,
                                                 mask, probsH, Wv1aT, HiH, GT);

  // 3) hidden = relu([probs|HjH] @ [GT_b; Wv1bT]^T + bv1)  (K=1536, z=2)
  mfma_gemm_kernel<false, true, true, true, false, true>
      <<<dim3(16, 8, 2), 512, 0, stream>>>(
      probsH, HjH, GT, Wv1bT, bv1, nullptr, hidH,
      S_, HDIM, S_, HDIM,
      (long)S_ * S_, (long)S_ * HDIM, (long)HDIM * S_, (long)S_ * HDIM);

  // 4) out = alpha * (hidden @ Wv2 + bv2)   (K=1024, 256 blocks, XCD swizzle)
  mfma_gemm_kernel<true, false, false, false, true, false>
      <<<dim3(256), 512, 0, stream>>>(
      hidH, nullptr, Wv2T, nullptr, bv2, alpha, out,
      ROWS, HDIM, HDIM, 0, 0, 0, 0, 0);
}